// Round 2
// baseline (890.106 us; speedup 1.0000x reference)
//
#include <hip/hip_runtime.h>
#include <hip/hip_bf16.h>
#include <math.h>

using bf16 = __hip_bfloat16;
typedef __bf16 v8bf __attribute__((ext_vector_type(8)));
typedef float v4f __attribute__((ext_vector_type(4)));

#define B_ 4
#define L_ 4096
#define D_ 1024
#define M_ (B_*L_)
#define CCH 32
#define LCH (L_/CCH)

__device__ __forceinline__ float bf2f(bf16 v){ return __bfloat162float(v); }
__device__ __forceinline__ bf16 f2bf(float v){ return __float2bfloat16(v); }

// ---------------- x fp32 -> bf16 ----------------
__global__ void k_cvt(const float* __restrict__ in, bf16* __restrict__ out, int n){
  int i = (blockIdx.x*256 + threadIdx.x)*4;
  float4 v = *(const float4*)(in + i);
  out[i]   = f2bf(v.x);
  out[i+1] = f2bf(v.y);
  out[i+2] = f2bf(v.z);
  out[i+3] = f2bf(v.w);
}

// ---------------- weight convert+transpose fp32 (R x C) -> bf16 (C x R) ----------------
__global__ void k_ctr(const float* __restrict__ in, bf16* __restrict__ out, int R, int C){
  __shared__ float tile[32][33];
  int c0 = blockIdx.x*32, r0 = blockIdx.y*32;
  #pragma unroll
  for (int i=0;i<32;i+=8)
    tile[threadIdx.y+i][threadIdx.x] = in[(size_t)(r0+threadIdx.y+i)*C + c0+threadIdx.x];
  __syncthreads();
  #pragma unroll
  for (int i=0;i<32;i+=8)
    out[(size_t)(c0+threadIdx.y+i)*R + r0+threadIdx.x] = f2bf(tile[threadIdx.x][threadIdx.y+i]);
}

// ---------------- MFMA GEMM: C[M,N] = epi(A[M,K] @ Bt[N,K]^T + bias) ----------------
// epi: 0 = store bf16; 1 = keyphase (tanh*pi -> cos to out0, sin to out1);
//      2 = exact gelu (bf16); 3 = + fp32 resid, store fp32 (final output)
// concat: A is x (lda=1024); for kk>=1024 read row m-1 (zero when l==0), col kk-1024.
#define BM 128
#define BN 128
#define BK 32
#define LDT 40   // +8 bf16 pad -> 80B row stride

__global__ __launch_bounds__(256) void k_gemm(
    const bf16* __restrict__ A, int lda,
    const bf16* __restrict__ Bt, int ldb,
    const float* __restrict__ bias,
    bf16* __restrict__ out0, bf16* __restrict__ out1,
    float* __restrict__ outf, const float* __restrict__ residf,
    int N, int Ktot, int epi, int concat)
{
  __shared__ ushort As[BM][LDT];
  __shared__ ushort Bs[BN][LDT];
  int tid = threadIdx.x;
  int lane = tid & 63, wave = tid >> 6;
  int wm = wave & 1, wn = wave >> 1;
  int bm = blockIdx.x * BM, bn = blockIdx.y * BN;

  v4f zero = {0.0f,0.0f,0.0f,0.0f};
  v4f acc[4][4];
  #pragma unroll
  for (int i=0;i<4;i++)
    #pragma unroll
    for (int j=0;j<4;j++) acc[i][j] = zero;

  int r = tid >> 1;
  int cseg = (tid & 1) * 16;

  for (int kk = 0; kk < Ktot; kk += BK) {
    // stage A tile (128 x 32)
    {
      int m = bm + r;
      bool zer = false;
      size_t off;
      if (concat && kk >= D_) {
        int l = m & (L_-1);
        if (l == 0) zer = true;
        off = (size_t)(m-1)*lda + (size_t)(kk - D_) + cseg;
      } else {
        off = (size_t)m*lda + (size_t)kk + cseg;
      }
      uint4 d0, d1;
      if (zer) { d0 = make_uint4(0u,0u,0u,0u); d1 = d0; }
      else {
        const uint4* p = (const uint4*)(A + off);
        d0 = p[0]; d1 = p[1];
      }
      *(uint4*)&As[r][cseg]   = d0;
      *(uint4*)&As[r][cseg+8] = d1;
    }
    // stage B tile (128 x 32) from N-major Bt
    {
      int n = bn + r;
      const uint4* p = (const uint4*)(Bt + (size_t)n*ldb + (size_t)kk + cseg);
      *(uint4*)&Bs[r][cseg]   = p[0];
      *(uint4*)&Bs[r][cseg+8] = p[1];
    }
    __syncthreads();
    int g4 = lane >> 4, mr = lane & 15;
    v8bf af[4], bfr[4];
    #pragma unroll
    for (int i=0;i<4;i++) af[i]  = *(const v8bf*)&As[wm*64 + i*16 + mr][g4*8];
    #pragma unroll
    for (int j=0;j<4;j++) bfr[j] = *(const v8bf*)&Bs[wn*64 + j*16 + mr][g4*8];
    #pragma unroll
    for (int i=0;i<4;i++)
      #pragma unroll
      for (int j=0;j<4;j++)
        acc[i][j] = __builtin_amdgcn_mfma_f32_16x16x32_bf16(af[i], bfr[j], acc[i][j], 0, 0, 0);
    __syncthreads();
  }

  // epilogue: C/D layout col=lane&15, row=(lane>>4)*4+reg  [verified m89/m91]
  int lr = lane >> 4, lc = lane & 15;
  #pragma unroll
  for (int i=0;i<4;i++){
    #pragma unroll
    for (int j=0;j<4;j++){
      int col  = bn + wn*64 + j*16 + lc;
      int row0 = bm + wm*64 + i*16 + lr*4;
      float bias_v = bias[col];
      #pragma unroll
      for (int rr=0; rr<4; rr++){
        int row = row0 + rr;
        size_t idx = (size_t)row*N + col;
        float v = acc[i][j][rr] + bias_v;
        if (epi == 0) {
          out0[idx] = f2bf(v);
        } else if (epi == 1) {
          float t = tanhf(v) * 3.14159265358979323846f;
          float s, c;
          __sincosf(t, &s, &c);
          out0[idx] = f2bf(c);
          out1[idx] = f2bf(s);
        } else if (epi == 2) {
          float gl = 0.5f*v*(1.0f + erff(v*0.70710678118654752f));
          out0[idx] = f2bf(gl);
        } else {
          outf[idx] = v + residf[idx];
        }
      }
    }
  }
}

// ---------------- gate scalar: g = sigmoid(GH . Wg2 + bg2), per token ----------------
__global__ void k_gate(const bf16* __restrict__ GH, const float* __restrict__ Wg2,
                       const float* __restrict__ bg2, float* __restrict__ g){
  __shared__ float red[256];
  int t = blockIdx.x, tid = threadIdx.x;
  const bf16* row = GH + (size_t)t*D_;
  float s = 0.0f;
  for (int k = tid; k < D_; k += 256) s += bf2f(row[k]) * Wg2[k];
  red[tid] = s; __syncthreads();
  for (int o=128;o>0;o>>=1){ if(tid<o) red[tid]+=red[tid+o]; __syncthreads(); }
  if (tid==0){
    float v = red[0] + bg2[0];
    g[t] = 1.0f/(1.0f+expf(-v));
  }
}

// ---------------- blend weights: softmax2(BH . Wb2 + bb2), per token ----------------
__global__ void k_bw(const bf16* __restrict__ BH, const float* __restrict__ Wb2,
                     const float* __restrict__ bb2, float2* __restrict__ bw){
  __shared__ float r0[256], r1[256];
  int t = blockIdx.x, tid = threadIdx.x;
  const bf16* row = BH + (size_t)t*(D_/2);
  float s0=0.0f, s1=0.0f;
  for (int k=tid;k<D_/2;k+=256){
    float v = bf2f(row[k]);
    s0 += v*Wb2[2*k];
    s1 += v*Wb2[2*k+1];
  }
  r0[tid]=s0; r1[tid]=s1; __syncthreads();
  for (int o=128;o>0;o>>=1){ if(tid<o){r0[tid]+=r0[tid+o]; r1[tid]+=r1[tid+o];} __syncthreads(); }
  if (tid==0){
    float a = r0[0]+bb2[0], b = r1[0]+bb2[1];
    float m = fmaxf(a,b);
    float e0 = expf(a-m), e1 = expf(b-m);
    float inv = 1.0f/(e0+e1);
    bw[t] = make_float2(e0*inv, e1*inv);
  }
}

// ---------------- gate cumsum over L, one block per batch ----------------
__global__ void k_gscan(const float* __restrict__ g, float* __restrict__ gc){
  __shared__ float buf[256];
  int b = blockIdx.x, tid = threadIdx.x;
  float carry = 0.0f;
  for (int t0=0;t0<L_;t0+=256){
    float v = g[b*L_ + t0 + tid];
    buf[tid] = v; __syncthreads();
    for (int o=1;o<256;o<<=1){
      float add = (tid>=o) ? buf[tid-o] : 0.0f;
      __syncthreads();
      buf[tid] += add;
      __syncthreads();
    }
    float tot = buf[255];
    gc[b*L_ + t0 + tid] = buf[tid] + carry;
    carry += tot;
    __syncthreads();
  }
}

// ---------------- scan pass 1: per-chunk partial sums ----------------
__global__ void k_scan_partial(const bf16* __restrict__ PV, const bf16* __restrict__ KV,
                               const bf16* __restrict__ KC, const bf16* __restrict__ KS,
                               const float* __restrict__ g, const float* __restrict__ phases,
                               float* __restrict__ PS){
  int tid = threadIdx.x;
  int d = blockIdx.x*256 + tid;
  int j = blockIdx.y, b = blockIdx.z;
  int l0 = j*LCH;
  float pkc=0.0f, pks=0.0f;
  if (l0 > 0){
    size_t pidx = ((size_t)b*L_ + l0-1)*D_ + d;
    pkc = bf2f(KC[pidx]); pks = bf2f(KS[pidx]);
  }
  float p0=0,p1=0,p2=0,p3=0;
  for (int l=l0; l<l0+LCH; l++){
    size_t idx = ((size_t)b*L_ + l)*D_ + d;
    float pv = bf2f(PV[idx]), kv = bf2f(KV[idx]);
    float kc = bf2f(KC[idx]), ks = bf2f(KS[idx]);
    float gl = g[b*L_ + l];
    float ph = phases[(size_t)l*D_ + d];
    float sn, cs; __sincosf(ph, &sn, &cs);
    float kvg = kv*gl;
    p0 += cs*pv; p1 += sn*pv; p2 += pkc*kvg; p3 += pks*kvg;
    pkc = kc; pks = ks;
  }
  size_t base = ((size_t)b*CCH + j)*D_ + d;
  size_t plane = (size_t)B_*CCH*D_;
  PS[0*plane + base] = p0;
  PS[1*plane + base] = p1;
  PS[2*plane + base] = p2;
  PS[3*plane + base] = p3;
}

// ---------------- exclusive prefix over chunks (in place) ----------------
__global__ void k_prefix(float* __restrict__ PS){
  int tid = threadIdx.x;
  int idx = blockIdx.x*256 + tid;      // over B_*D_
  int b = idx / D_, d = idx % D_;
  size_t plane = (size_t)B_*CCH*D_;
  for (int q=0;q<4;q++){
    float s = 0.0f;
    for (int j=0;j<CCH;j++){
      size_t p = (size_t)q*plane + ((size_t)b*CCH + j)*D_ + d;
      float v = PS[p];
      PS[p] = s;
      s += v;
    }
  }
}

// ---------------- scan pass 2: apply with carry, emit blended ----------------
__global__ void k_scan_apply(const bf16* __restrict__ PV, const bf16* __restrict__ KV,
                             const bf16* __restrict__ KC, const bf16* __restrict__ KS,
                             const float* __restrict__ g, const float* __restrict__ phases,
                             const float* __restrict__ PS, const float* __restrict__ gc,
                             const float2* __restrict__ bw, bf16* __restrict__ BL){
  int tid = threadIdx.x;
  int d = blockIdx.x*256 + tid;
  int j = blockIdx.y, b = blockIdx.z;
  int l0 = j*LCH;
  size_t base = ((size_t)b*CCH + j)*D_ + d;
  size_t plane = (size_t)B_*CCH*D_;
  float mc  = PS[0*plane+base], ms  = PS[1*plane+base];
  float kcm = PS[2*plane+base], ksm = PS[3*plane+base];
  float pkc=0.0f, pks=0.0f;
  if (l0 > 0){
    size_t pidx = ((size_t)b*L_ + l0-1)*D_ + d;
    pkc = bf2f(KC[pidx]); pks = bf2f(KS[pidx]);
  }
  for (int l=l0; l<l0+LCH; l++){
    size_t idx = ((size_t)b*L_ + l)*D_ + d;
    float pv = bf2f(PV[idx]), kv = bf2f(KV[idx]);
    float kc = bf2f(KC[idx]), ks = bf2f(KS[idx]);
    float gl = g[b*L_ + l];
    float ph = phases[(size_t)l*D_ + d];
    float sn, cs; __sincosf(ph, &sn, &cs);
    mc += cs*pv; ms += sn*pv;
    float pos_ret = (cs*mc + sn*ms) * 0.03125f;
    float kvg = kv*gl;
    kcm += pkc*kvg; ksm += pks*kvg;
    float gcv = fmaxf(gc[b*L_+l], 1.0f);
    float kv_ret = (kc*kcm + ks*ksm) * (0.03125f * rsqrtf(gcv));
    float2 w = bw[b*L_+l];
    BL[idx] = f2bf(w.x*pos_ret + w.y*kv_ret);
    pkc = kc; pks = ks;
  }
}

// ---------------- LayerNorm over D, per token (in-place safe: reads row to regs first) ----
__global__ void k_ln(const bf16* __restrict__ BL, const float* __restrict__ ln_g,
                     const float* __restrict__ ln_b, bf16* __restrict__ LNB){
  __shared__ float r0[256], r1[256];
  int t = blockIdx.x, tid = threadIdx.x;
  const bf16* row = BL + (size_t)t*D_;
  float v[4]; float s=0.0f, s2=0.0f;
  #pragma unroll
  for (int i=0;i<4;i++){ v[i] = bf2f(row[tid + i*256]); s += v[i]; s2 += v[i]*v[i]; }
  r0[tid]=s; r1[tid]=s2; __syncthreads();
  for (int o=128;o>0;o>>=1){ if(tid<o){r0[tid]+=r0[tid+o]; r1[tid]+=r1[tid+o];} __syncthreads(); }
  float mu  = r0[0]*(1.0f/D_);
  float var = r1[0]*(1.0f/D_) - mu*mu;
  float rstd = rsqrtf(var + 1e-5f);
  bf16* orow = LNB + (size_t)t*D_;
  #pragma unroll
  for (int i=0;i<4;i++){
    int d = tid + i*256;
    orow[d] = f2bf((v[i]-mu)*rstd*ln_g[d] + ln_b[d]);
  }
}

extern "C" void kernel_launch(void* const* d_in, const int* in_sizes, int n_in,
                              void* d_out, int out_size, void* d_ws, size_t ws_size,
                              hipStream_t stream) {
  const float* x     = (const float*)d_in[0];
  const float* phases= (const float*)d_in[1];
  const float* Wpv   = (const float*)d_in[2];
  const float* bpv   = (const float*)d_in[3];
  const float* Wk    = (const float*)d_in[4];
  const float* bk    = (const float*)d_in[5];
  const float* Wkv   = (const float*)d_in[6];
  const float* bkv   = (const float*)d_in[7];
  const float* Wg1   = (const float*)d_in[8];
  const float* bg1   = (const float*)d_in[9];
  const float* Wg2   = (const float*)d_in[10];
  const float* bg2   = (const float*)d_in[11];
  const float* Wb1   = (const float*)d_in[12];
  const float* bb1   = (const float*)d_in[13];
  const float* Wb2   = (const float*)d_in[14];
  const float* bb2   = (const float*)d_in[15];
  const float* ln_g  = (const float*)d_in[16];
  const float* ln_b  = (const float*)d_in[17];
  const float* Wo    = (const float*)d_in[18];
  const float* bo    = (const float*)d_in[19];
  float* out = (float*)d_out;

  char* ws = (char*)d_ws;
  size_t off = 0;
  auto alloc = [&](size_t bytes)->char*{
    char* p = ws + off; off += (bytes + 255) & ~(size_t)255; return p;
  };
  bf16* xb   = (bf16*)alloc((size_t)M_*D_*2);
  bf16* WpvT = (bf16*)alloc((size_t)D_*D_*2);
  bf16* WkT  = (bf16*)alloc((size_t)D_*D_*2);
  bf16* WkvT = (bf16*)alloc((size_t)D_*D_*2);
  bf16* Wg1T = (bf16*)alloc((size_t)2*D_*D_*2);
  bf16* Wb1T = (bf16*)alloc((size_t)D_*(D_/2)*2);
  bf16* WoT  = (bf16*)alloc((size_t)D_*D_*2);
  bf16* PV   = (bf16*)alloc((size_t)M_*D_*2);
  bf16* KC   = (bf16*)alloc((size_t)M_*D_*2);
  bf16* KS   = (bf16*)alloc((size_t)M_*D_*2);
  bf16* KV   = (bf16*)alloc((size_t)M_*D_*2);
  bf16* GH   = (bf16*)alloc((size_t)M_*D_*2);   // reused as BL, then LNB (in-place LN)
  bf16* BH   = (bf16*)alloc((size_t)M_*(D_/2)*2);
  float* gbuf  = (float*)alloc((size_t)M_*4);
  float* gcbuf = (float*)alloc((size_t)M_*4);
  float2* bwbuf= (float2*)alloc((size_t)M_*8);
  float* PS    = (float*)alloc((size_t)4*B_*CCH*D_*4);
  bf16* BL  = GH;
  bf16* LNB = GH;

  // x -> bf16
  k_cvt<<<(M_*D_)/1024, 256, 0, stream>>>(x, xb, M_*D_);

  dim3 tb(32,8);
  k_ctr<<<dim3(D_/32, D_/32), tb, 0, stream>>>(Wpv, WpvT, D_, D_);
  k_ctr<<<dim3(D_/32, D_/32), tb, 0, stream>>>(Wk,  WkT,  D_, D_);
  k_ctr<<<dim3(D_/32, D_/32), tb, 0, stream>>>(Wkv, WkvT, D_, D_);
  k_ctr<<<dim3(D_/32, 2*D_/32), tb, 0, stream>>>(Wg1, Wg1T, 2*D_, D_);
  k_ctr<<<dim3((D_/2)/32, D_/32), tb, 0, stream>>>(Wb1, Wb1T, D_, D_/2);
  k_ctr<<<dim3(D_/32, D_/32), tb, 0, stream>>>(Wo,  WoT,  D_, D_);

  dim3 gg(M_/BM, D_/BN);
  // PV = x@Wpv + bpv
  k_gemm<<<gg,256,0,stream>>>(xb, D_, WpvT, D_, bpv, PV, nullptr, nullptr, nullptr, D_, D_, 0, 0);
  // key_cos/key_sin = cos/sin(tanh(x@Wk+bk)*pi)
  k_gemm<<<gg,256,0,stream>>>(xb, D_, WkT, D_, bk, KC, KS, nullptr, nullptr, D_, D_, 1, 0);
  // KV = x@Wkv + bkv
  k_gemm<<<gg,256,0,stream>>>(xb, D_, WkvT, D_, bkv, KV, nullptr, nullptr, nullptr, D_, D_, 0, 0);
  // GH = gelu([x, shift1(x)]@Wg1 + bg1)   (K=2048, concat mode)
  k_gemm<<<gg,256,0,stream>>>(xb, D_, Wg1T, 2*D_, bg1, GH, nullptr, nullptr, nullptr, D_, 2*D_, 2, 1);
  // g = sigmoid(GH@Wg2 + bg2)
  k_gate<<<M_,256,0,stream>>>(GH, Wg2, bg2, gbuf);
  // BH = gelu(x@Wb1 + bb1)
  dim3 gb(M_/BM, (D_/2)/BN);
  k_gemm<<<gb,256,0,stream>>>(xb, D_, Wb1T, D_, bb1, BH, nullptr, nullptr, nullptr, D_/2, D_, 2, 0);
  // bw = softmax2(BH@Wb2 + bb2)
  k_bw<<<M_,256,0,stream>>>(BH, Wb2, bb2, bwbuf);
  // gate cumsum
  k_gscan<<<B_,256,0,stream>>>(gbuf, gcbuf);
  // chunked scans -> blended (overwrites GH)
  dim3 sg(D_/256, CCH, B_);
  k_scan_partial<<<sg,256,0,stream>>>(PV, KV, KC, KS, gbuf, phases, PS);
  k_prefix<<<(B_*D_)/256,256,0,stream>>>(PS);
  k_scan_apply<<<sg,256,0,stream>>>(PV, KV, KC, KS, gbuf, phases, PS, gcbuf, bwbuf, BL);
  // LayerNorm (in-place)
  k_ln<<<M_,256,0,stream>>>(BL, ln_g, ln_b, LNB);
  // out = x + LN@Wo + bo   (fp32 out, fp32 resid)
  k_gemm<<<gg,256,0,stream>>>(LNB, D_, WoT, D_, bo, nullptr, nullptr, out, x, D_, D_, 3, 0);
}

// Round 3
// 769.383 us; speedup vs baseline: 1.1569x; 1.1569x over previous
//
#include <hip/hip_runtime.h>
#include <hip/hip_bf16.h>
#include <math.h>

using bf16 = __hip_bfloat16;
typedef __bf16 v8bf __attribute__((ext_vector_type(8)));
typedef float v4f __attribute__((ext_vector_type(4)));

#define B_ 4
#define L_ 4096
#define D_ 1024
#define M_ (B_*L_)
#define CCH 128
#define LCH (L_/CCH)
#define NF 3584   // fused N: Wpv(1024) | Wk(1024) | Wkv(1024) | Wb1(512)

__device__ __forceinline__ float bf2f(bf16 v){ return __bfloat162float(v); }
__device__ __forceinline__ bf16 f2bf(float v){ return __float2bfloat16(v); }
__device__ __forceinline__ float us2f(ushort u){ union{unsigned u32; float f;}c; c.u32=((unsigned)u)<<16; return c.f; }
__device__ __forceinline__ ushort f2us(float v){ bf16 h=__float2bfloat16(v); return *(ushort*)&h; }

// async global->LDS, 16B per lane, dest = uniform base + lane*16  [m97 pattern]
__device__ __forceinline__ void g2l16(const void* g, void* l){
  __builtin_amdgcn_global_load_lds(
    (const __attribute__((address_space(1))) unsigned int*)g,
    (__attribute__((address_space(3))) unsigned int*)l, 16, 0, 0);
}

// ---------------- zero the redirect buffer (ws is poisoned 0xAA each launch) ----------------
__global__ void k_zero(ushort* z){ z[threadIdx.x] = 0; }

// ---------------- x fp32 -> bf16 ----------------
__global__ void k_cvt(const float* __restrict__ in, bf16* __restrict__ out, int n){
  int i = (blockIdx.x*256 + threadIdx.x)*4;
  float4 v = *(const float4*)(in + i);
  out[i]   = f2bf(v.x);
  out[i+1] = f2bf(v.y);
  out[i+2] = f2bf(v.z);
  out[i+3] = f2bf(v.w);
}

// ---------------- weight convert+transpose fp32 (R x C) -> bf16 (C x R) ----------------
__global__ void k_ctr(const float* __restrict__ in, bf16* __restrict__ out, int R, int C){
  __shared__ float tile[32][33];
  int c0 = blockIdx.x*32, r0 = blockIdx.y*32;
  #pragma unroll
  for (int i=0;i<32;i+=8)
    tile[threadIdx.y+i][threadIdx.x] = in[(size_t)(r0+threadIdx.y+i)*C + c0+threadIdx.x];
  __syncthreads();
  #pragma unroll
  for (int i=0;i<32;i+=8)
    out[(size_t)(c0+threadIdx.y+i)*R + r0+threadIdx.x] = f2bf(tile[threadIdx.x][threadIdx.y+i]);
}

// ---------------- pack fused bias [bpv|bk|bkv|bb1] ----------------
__global__ void k_pack_bias(const float* __restrict__ bpv, const float* __restrict__ bk,
                            const float* __restrict__ bkv, const float* __restrict__ bb1,
                            float* __restrict__ bf){
  int i = blockIdx.x*256 + threadIdx.x;
  float v;
  if (i < 1024) v = bpv[i];
  else if (i < 2048) v = bk[i-1024];
  else if (i < 3072) v = bkv[i-2048];
  else v = bb1[i-3072];
  bf[i] = v;
}

// ---------------- MFMA GEMM, global_load_lds staging (m97 structure) ----------------
// EPI: 2 = exact-gelu -> o0 (bf16, stride N)
//      3 = + fp32 resid -> outf (fp32, stride N)
//      4 = fused: col<1024 -> o0=PV; <2048 -> keyphase o1=KC,o2=KS; <3072 -> o3=KV; else gelu o4=BH(stride 512)
// CONCAT: A is x; for kk>=1024 read row m-1 col kk-1024, zero when (m % L)==0 (via zeros redirect).
#define BM 128
#define BN 128
#define BK 32

template<int EPI, bool CONCAT>
__global__ __launch_bounds__(256) void k_gemm(
    const bf16* __restrict__ A, int lda,
    const bf16* __restrict__ Bt, int ldb,
    const float* __restrict__ bias,
    const bf16* __restrict__ zeros,
    bf16* __restrict__ o0, bf16* __restrict__ o1, bf16* __restrict__ o2,
    bf16* __restrict__ o3, bf16* __restrict__ o4,
    float* __restrict__ outf, const float* __restrict__ residf,
    int N, int Ktot)
{
  __shared__ __align__(16) ushort As[BM*BK];   // 128 rows x 32 (64B/row), unpadded
  __shared__ __align__(16) ushort Bs[BN*BK];
  int tid = threadIdx.x;
  int lane = tid & 63, wave = tid >> 6;
  int wm = wave & 1, wn = wave >> 1;
  int bn = blockIdx.x * BN, bm = blockIdx.y * BM;

  v4f zero = {0.f,0.f,0.f,0.f};
  v4f acc[4][4];
  #pragma unroll
  for (int i=0;i<4;i++)
    #pragma unroll
    for (int j=0;j<4;j++) acc[i][j] = zero;

  int sub = lane >> 2;        // 0..15 row-within-chunk
  int seg = lane & 3;         // 16B segment
  int mr = lane & 15, g4 = lane >> 4;

  for (int kk = 0; kk < Ktot; kk += BK) {
    // each wave issues 4 async 1KB stages (chunk q = wave*4+s; q<8 -> A rows q*16.., else B)
    #pragma unroll
    for (int s=0;s<4;s++){
      int q = wave*4 + s;
      if (q < 8){
        int row = q*16 + sub;
        int m = bm + row;
        const bf16* src;
        if (CONCAT && kk >= D_){
          int l = m & (L_-1);
          src = (l==0) ? (zeros + seg*8)
                       : (A + (size_t)(m-1)*lda + (size_t)(kk - D_) + seg*8);
        } else {
          src = A + (size_t)m*lda + (size_t)kk + seg*8;
        }
        g2l16(src, As + q*512);
      } else {
        int row = (q-8)*16 + sub;
        int n = bn + row;
        const bf16* src = Bt + (size_t)n*ldb + (size_t)kk + seg*8;
        g2l16(src, Bs + (q-8)*512);
      }
    }
    __syncthreads();   // drains vmcnt -> LDS visible
    v8bf af[4], bfr[4];
    #pragma unroll
    for (int i=0;i<4;i++) af[i]  = *(const v8bf*)&As[(wm*64 + i*16 + mr)*BK + g4*8];
    #pragma unroll
    for (int j=0;j<4;j++) bfr[j] = *(const v8bf*)&Bs[(wn*64 + j*16 + mr)*BK + g4*8];
    #pragma unroll
    for (int i=0;i<4;i++)
      #pragma unroll
      for (int j=0;j<4;j++)
        acc[i][j] = __builtin_amdgcn_mfma_f32_16x16x32_bf16(af[i], bfr[j], acc[i][j], 0, 0, 0);
    __syncthreads();
  }

  // epilogue: C/D layout col=lane&15, row=(lane>>4)*4+reg  [verified m89/m91]
  int lr = lane >> 4, lc = lane & 15;
  #pragma unroll
  for (int i=0;i<4;i++){
    #pragma unroll
    for (int j=0;j<4;j++){
      int col  = bn + wn*64 + j*16 + lc;
      int row0 = bm + wm*64 + i*16 + lr*4;
      float bias_v = bias[col];
      #pragma unroll
      for (int rr=0; rr<4; rr++){
        int row = row0 + rr;
        float v = acc[i][j][rr] + bias_v;
        if (EPI == 2) {
          float gl = 0.5f*v*(1.0f + erff(v*0.70710678118654752f));
          o0[(size_t)row*N + col] = f2bf(gl);
        } else if (EPI == 3) {
          size_t idx = (size_t)row*N + col;
          outf[idx] = v + residf[idx];
        } else { // EPI == 4, block-uniform branch
          if (col < 1024) {
            o0[(size_t)row*1024 + col] = f2bf(v);
          } else if (col < 2048) {
            float t = tanhf(v) * 3.14159265358979323846f;
            float sn, cs; __sincosf(t, &sn, &cs);
            size_t idx = (size_t)row*1024 + (col-1024);
            o1[idx] = f2bf(cs);
            o2[idx] = f2bf(sn);
          } else if (col < 3072) {
            o3[(size_t)row*1024 + (col-2048)] = f2bf(v);
          } else {
            float gl = 0.5f*v*(1.0f + erff(v*0.70710678118654752f));
            o4[(size_t)row*512 + (col-3072)] = f2bf(gl);
          }
        }
      }
    }
  }
}

// ---------------- gate scalar: g = sigmoid(GH . Wg2 + bg2), per token ----------------
__global__ void k_gate(const bf16* __restrict__ GH, const float* __restrict__ Wg2,
                       const float* __restrict__ bg2, float* __restrict__ g){
  __shared__ float red[256];
  int t = blockIdx.x, tid = threadIdx.x;
  const ushort* row = (const ushort*)(GH + (size_t)t*D_);
  int k0 = tid*4;
  ushort4 u = *(const ushort4*)&row[k0];
  float4 w = *(const float4*)&Wg2[k0];
  float s = us2f(u.x)*w.x + us2f(u.y)*w.y + us2f(u.z)*w.z + us2f(u.w)*w.w;
  red[tid] = s; __syncthreads();
  for (int o=128;o>0;o>>=1){ if(tid<o) red[tid]+=red[tid+o]; __syncthreads(); }
  if (tid==0){
    float v = red[0] + bg2[0];
    g[t] = 1.0f/(1.0f+expf(-v));
  }
}

// ---------------- blend weights: softmax2(BH . Wb2 + bb2), per token ----------------
__global__ void k_bw(const bf16* __restrict__ BH, const float* __restrict__ Wb2,
                     const float* __restrict__ bb2, float2* __restrict__ bw){
  __shared__ float r0[256], r1[256];
  int t = blockIdx.x, tid = threadIdx.x;
  const ushort* row = (const ushort*)(BH + (size_t)t*(D_/2));
  int k0 = tid*2;
  ushort2 u = *(const ushort2*)&row[k0];
  float4 w = *(const float4*)&Wb2[2*k0];
  float s0 = us2f(u.x)*w.x + us2f(u.y)*w.z;
  float s1 = us2f(u.x)*w.y + us2f(u.y)*w.w;
  r0[tid]=s0; r1[tid]=s1; __syncthreads();
  for (int o=128;o>0;o>>=1){ if(tid<o){r0[tid]+=r0[tid+o]; r1[tid]+=r1[tid+o];} __syncthreads(); }
  if (tid==0){
    float a = r0[0]+bb2[0], b = r1[0]+bb2[1];
    float m = fmaxf(a,b);
    float e0 = expf(a-m), e1 = expf(b-m);
    float inv = 1.0f/(e0+e1);
    bw[t] = make_float2(e0*inv, e1*inv);
  }
}

// ---------------- gate cumsum over L, one block per batch ----------------
__global__ void k_gscan(const float* __restrict__ g, float* __restrict__ gc){
  __shared__ float buf[256];
  int b = blockIdx.x, tid = threadIdx.x;
  float carry = 0.0f;
  for (int t0=0;t0<L_;t0+=256){
    float v = g[b*L_ + t0 + tid];
    buf[tid] = v; __syncthreads();
    for (int o=1;o<256;o<<=1){
      float add = (tid>=o) ? buf[tid-o] : 0.0f;
      __syncthreads();
      buf[tid] += add;
      __syncthreads();
    }
    float tot = buf[255];
    gc[b*L_ + t0 + tid] = buf[tid] + carry;
    carry += tot;
    __syncthreads();
  }
}

// ---------------- scan pass 1: per-chunk partial sums (4 channels/thread) ----------------
__global__ void k_scan_partial(const bf16* __restrict__ PV, const bf16* __restrict__ KV,
                               const bf16* __restrict__ KC, const bf16* __restrict__ KS,
                               const float* __restrict__ g, const float* __restrict__ phases,
                               float* __restrict__ PS){
  int tid = threadIdx.x;
  int d0 = tid*4;
  int j = blockIdx.x, b = blockIdx.y;
  int l0 = j*LCH;
  float pkc[4]={0,0,0,0}, pks[4]={0,0,0,0};
  if (l0 > 0){
    size_t pidx = ((size_t)b*L_ + l0-1)*D_ + d0;
    ushort4 uc = *(const ushort4*)(KC+pidx), us = *(const ushort4*)(KS+pidx);
    pkc[0]=us2f(uc.x); pkc[1]=us2f(uc.y); pkc[2]=us2f(uc.z); pkc[3]=us2f(uc.w);
    pks[0]=us2f(us.x); pks[1]=us2f(us.y); pks[2]=us2f(us.z); pks[3]=us2f(us.w);
  }
  float p0[4]={0,0,0,0}, p1[4]={0,0,0,0}, p2[4]={0,0,0,0}, p3[4]={0,0,0,0};
  for (int l=l0; l<l0+LCH; l++){
    size_t idx = ((size_t)b*L_ + l)*D_ + d0;
    ushort4 upv = *(const ushort4*)(PV+idx);
    ushort4 ukv = *(const ushort4*)(KV+idx);
    ushort4 ukc = *(const ushort4*)(KC+idx);
    ushort4 uks = *(const ushort4*)(KS+idx);
    float4 ph = *(const float4*)&phases[(size_t)l*D_ + d0];
    float gl = g[b*L_ + l];
    float pvv[4]={us2f(upv.x),us2f(upv.y),us2f(upv.z),us2f(upv.w)};
    float kvv[4]={us2f(ukv.x),us2f(ukv.y),us2f(ukv.z),us2f(ukv.w)};
    float kcv[4]={us2f(ukc.x),us2f(ukc.y),us2f(ukc.z),us2f(ukc.w)};
    float ksv[4]={us2f(uks.x),us2f(uks.y),us2f(uks.z),us2f(uks.w)};
    float phv[4]={ph.x,ph.y,ph.z,ph.w};
    #pragma unroll
    for (int c=0;c<4;c++){
      float sn, cs; __sincosf(phv[c], &sn, &cs);
      float kvg = kvv[c]*gl;
      p0[c] += cs*pvv[c]; p1[c] += sn*pvv[c];
      p2[c] += pkc[c]*kvg; p3[c] += pks[c]*kvg;
      pkc[c]=kcv[c]; pks[c]=ksv[c];
    }
  }
  size_t base = ((size_t)b*CCH + j)*D_ + d0;
  size_t plane = (size_t)B_*CCH*D_;
  #pragma unroll
  for (int c=0;c<4;c++){
    PS[0*plane + base + c] = p0[c];
    PS[1*plane + base + c] = p1[c];
    PS[2*plane + base + c] = p2[c];
    PS[3*plane + base + c] = p3[c];
  }
}

// ---------------- exclusive prefix over chunks (in place) ----------------
__global__ void k_prefix(float* __restrict__ PS){
  int tid = threadIdx.x;
  int idx = blockIdx.x*256 + tid;      // over B_*D_
  int b = idx / D_, d = idx % D_;
  size_t plane = (size_t)B_*CCH*D_;
  for (int q=0;q<4;q++){
    float s = 0.0f;
    for (int j=0;j<CCH;j++){
      size_t p = (size_t)q*plane + ((size_t)b*CCH + j)*D_ + d;
      float v = PS[p];
      PS[p] = s;
      s += v;
    }
  }
}

// ---------------- scan pass 2: apply with carry, emit blended (4 ch/thread) ----------------
__global__ void k_scan_apply(const bf16* __restrict__ PV, const bf16* __restrict__ KV,
                             const bf16* __restrict__ KC, const bf16* __restrict__ KS,
                             const float* __restrict__ g, const float* __restrict__ phases,
                             const float* __restrict__ PS, const float* __restrict__ gc,
                             const float2* __restrict__ bw, bf16* __restrict__ BL){
  int tid = threadIdx.x;
  int d0 = tid*4;
  int j = blockIdx.x, b = blockIdx.y;
  int l0 = j*LCH;
  size_t base = ((size_t)b*CCH + j)*D_ + d0;
  size_t plane = (size_t)B_*CCH*D_;
  float mc[4], ms[4], kcm[4], ksm[4];
  #pragma unroll
  for (int c=0;c<4;c++){
    mc[c]  = PS[0*plane+base+c]; ms[c]  = PS[1*plane+base+c];
    kcm[c] = PS[2*plane+base+c]; ksm[c] = PS[3*plane+base+c];
  }
  float pkc[4]={0,0,0,0}, pks[4]={0,0,0,0};
  if (l0 > 0){
    size_t pidx = ((size_t)b*L_ + l0-1)*D_ + d0;
    ushort4 uc = *(const ushort4*)(KC+pidx), us = *(const ushort4*)(KS+pidx);
    pkc[0]=us2f(uc.x); pkc[1]=us2f(uc.y); pkc[2]=us2f(uc.z); pkc[3]=us2f(uc.w);
    pks[0]=us2f(us.x); pks[1]=us2f(us.y); pks[2]=us2f(us.z); pks[3]=us2f(us.w);
  }
  for (int l=l0; l<l0+LCH; l++){
    size_t idx = ((size_t)b*L_ + l)*D_ + d0;
    ushort4 upv = *(const ushort4*)(PV+idx);
    ushort4 ukv = *(const ushort4*)(KV+idx);
    ushort4 ukc = *(const ushort4*)(KC+idx);
    ushort4 uks = *(const ushort4*)(KS+idx);
    float4 ph = *(const float4*)&phases[(size_t)l*D_ + d0];
    float gl = g[b*L_ + l];
    float gcv = fmaxf(gc[b*L_+l], 1.0f);
    float rs = 0.03125f * rsqrtf(gcv);
    float2 w = bw[b*L_+l];
    float pvv[4]={us2f(upv.x),us2f(upv.y),us2f(upv.z),us2f(upv.w)};
    float kvv[4]={us2f(ukv.x),us2f(ukv.y),us2f(ukv.z),us2f(ukv.w)};
    float kcv[4]={us2f(ukc.x),us2f(ukc.y),us2f(ukc.z),us2f(ukc.w)};
    float ksv[4]={us2f(uks.x),us2f(uks.y),us2f(uks.z),us2f(uks.w)};
    float phv[4]={ph.x,ph.y,ph.z,ph.w};
    ushort4 ob;
    ushort* obp = (ushort*)&ob;
    #pragma unroll
    for (int c=0;c<4;c++){
      float sn, cs; __sincosf(phv[c], &sn, &cs);
      mc[c] += cs*pvv[c]; ms[c] += sn*pvv[c];
      float pos_ret = (cs*mc[c] + sn*ms[c]) * 0.03125f;
      float kvg = kvv[c]*gl;
      kcm[c] += pkc[c]*kvg; ksm[c] += pks[c]*kvg;
      float kv_ret = (kcv[c]*kcm[c] + ksv[c]*ksm[c]) * rs;
      obp[c] = f2us(w.x*pos_ret + w.y*kv_ret);
      pkc[c]=kcv[c]; pks[c]=ksv[c];
    }
    *(ushort4*)(BL + idx) = ob;
  }
}

// ---------------- LayerNorm over D, per token (in-place safe) ----------------
__global__ void k_ln(const bf16* __restrict__ BL, const float* __restrict__ ln_g,
                     const float* __restrict__ ln_b, bf16* __restrict__ LNB){
  __shared__ float r0[256], r1[256];
  int t = blockIdx.x, tid = threadIdx.x;
  int d0 = tid*4;
  ushort4 u = *(const ushort4*)((const ushort*)(BL + (size_t)t*D_) + d0);
  float v[4]={us2f(u.x),us2f(u.y),us2f(u.z),us2f(u.w)};
  float s=v[0]+v[1]+v[2]+v[3];
  float s2=v[0]*v[0]+v[1]*v[1]+v[2]*v[2]+v[3]*v[3];
  r0[tid]=s; r1[tid]=s2; __syncthreads();
  for (int o=128;o>0;o>>=1){ if(tid<o){r0[tid]+=r0[tid+o]; r1[tid]+=r1[tid+o];} __syncthreads(); }
  float mu  = r0[0]*(1.0f/D_);
  float var = r1[0]*(1.0f/D_) - mu*mu;
  float rstd = rsqrtf(var + 1e-5f);
  float4 gv = *(const float4*)&ln_g[d0];
  float4 bv = *(const float4*)&ln_b[d0];
  ushort4 ou;
  ou.x = f2us((v[0]-mu)*rstd*gv.x + bv.x);
  ou.y = f2us((v[1]-mu)*rstd*gv.y + bv.y);
  ou.z = f2us((v[2]-mu)*rstd*gv.z + bv.z);
  ou.w = f2us((v[3]-mu)*rstd*gv.w + bv.w);
  *(ushort4*)((ushort*)(LNB + (size_t)t*D_) + d0) = ou;
}

extern "C" void kernel_launch(void* const* d_in, const int* in_sizes, int n_in,
                              void* d_out, int out_size, void* d_ws, size_t ws_size,
                              hipStream_t stream) {
  const float* x     = (const float*)d_in[0];
  const float* phases= (const float*)d_in[1];
  const float* Wpv   = (const float*)d_in[2];
  const float* bpv   = (const float*)d_in[3];
  const float* Wk    = (const float*)d_in[4];
  const float* bk    = (const float*)d_in[5];
  const float* Wkv   = (const float*)d_in[6];
  const float* bkv   = (const float*)d_in[7];
  const float* Wg1   = (const float*)d_in[8];
  const float* bg1   = (const float*)d_in[9];
  const float* Wg2   = (const float*)d_in[10];
  const float* bg2   = (const float*)d_in[11];
  const float* Wb1   = (const float*)d_in[12];
  const float* bb1   = (const float*)d_in[13];
  const float* Wb2   = (const float*)d_in[14];
  const float* bb2   = (const float*)d_in[15];
  const float* ln_g  = (const float*)d_in[16];
  const float* ln_b  = (const float*)d_in[17];
  const float* Wo    = (const float*)d_in[18];
  const float* bo    = (const float*)d_in[19];
  float* out = (float*)d_out;

  char* ws = (char*)d_ws;
  size_t off = 0;
  auto alloc = [&](size_t bytes)->char*{
    char* p = ws + off; off += (bytes + 255) & ~(size_t)255; return p;
  };
  bf16* xb   = (bf16*)alloc((size_t)M_*D_*2);
  bf16* WfT  = (bf16*)alloc((size_t)NF*D_*2);       // [WpvT|WkT|WkvT|Wb1T], N-major, ld=1024
  bf16* Wg1T = (bf16*)alloc((size_t)D_*2*D_*2);     // 1024 x 2048
  bf16* WoT  = (bf16*)alloc((size_t)D_*D_*2);
  bf16* PV   = (bf16*)alloc((size_t)M_*D_*2);
  bf16* KC   = (bf16*)alloc((size_t)M_*D_*2);
  bf16* KS   = (bf16*)alloc((size_t)M_*D_*2);
  bf16* KV   = (bf16*)alloc((size_t)M_*D_*2);
  bf16* GH   = (bf16*)alloc((size_t)M_*D_*2);       // reused as BL then LNB
  bf16* BH   = (bf16*)alloc((size_t)M_*(D_/2)*2);
  float* gbuf  = (float*)alloc((size_t)M_*4);
  float* gcbuf = (float*)alloc((size_t)M_*4);
  float2* bwbuf= (float2*)alloc((size_t)M_*8);
  float* PS    = (float*)alloc((size_t)4*B_*CCH*D_*4);
  float* biasF = (float*)alloc((size_t)NF*4);
  bf16* zeros  = (bf16*)alloc(256);
  bf16* BL  = GH;
  bf16* LNB = GH;

  k_zero<<<1,128,0,stream>>>((ushort*)zeros);
  k_cvt<<<(M_*D_)/1024, 256, 0, stream>>>(x, xb, M_*D_);

  dim3 tb(32,8);
  k_ctr<<<dim3(D_/32, D_/32), tb, 0, stream>>>(Wpv, WfT,                         D_, D_);
  k_ctr<<<dim3(D_/32, D_/32), tb, 0, stream>>>(Wk,  WfT + (size_t)1024*D_,       D_, D_);
  k_ctr<<<dim3(D_/32, D_/32), tb, 0, stream>>>(Wkv, WfT + (size_t)2048*D_,       D_, D_);
  k_ctr<<<dim3((D_/2)/32, D_/32), tb, 0, stream>>>(Wb1, WfT + (size_t)3072*D_,   D_, D_/2);
  k_ctr<<<dim3(D_/32, 2*D_/32), tb, 0, stream>>>(Wg1, Wg1T, 2*D_, D_);
  k_ctr<<<dim3(D_/32, D_/32), tb, 0, stream>>>(Wo,  WoT,  D_, D_);
  k_pack_bias<<<NF/256,256,0,stream>>>(bpv, bk, bkv, bb1, biasF);

  // fused PV/KC,KS/KV/BH :  x @ [Wpv|Wk|Wkv|Wb1]  (M x 3584 x 1024)
  k_gemm<4,false><<<dim3(NF/BN, M_/BM),256,0,stream>>>(
      xb, D_, WfT, D_, biasF, zeros, PV, KC, KS, KV, BH, nullptr, nullptr, NF, D_);
  // GH = gelu([x, shift1(x)] @ Wg1 + bg1)  (K=2048, concat)
  k_gemm<2,true><<<dim3(D_/BN, M_/BM),256,0,stream>>>(
      xb, D_, Wg1T, 2*D_, bg1, zeros, GH, nullptr, nullptr, nullptr, nullptr, nullptr, nullptr, D_, 2*D_);
  // g = sigmoid(GH@Wg2 + bg2)
  k_gate<<<M_,256,0,stream>>>(GH, Wg2, bg2, gbuf);
  // bw = softmax2(BH@Wb2 + bb2)
  k_bw<<<M_,256,0,stream>>>(BH, Wb2, bb2, bwbuf);
  // gate cumsum
  k_gscan<<<B_,256,0,stream>>>(gbuf, gcbuf);
  // chunked scans -> blended (overwrites GH)
  dim3 sg(CCH, B_);
  k_scan_partial<<<sg,256,0,stream>>>(PV, KV, KC, KS, gbuf, phases, PS);
  k_prefix<<<(B_*D_)/256,256,0,stream>>>(PS);
  k_scan_apply<<<sg,256,0,stream>>>(PV, KV, KC, KS, gbuf, phases, PS, gcbuf, bwbuf, BL);
  // LayerNorm (in-place)
  k_ln<<<M_,256,0,stream>>>(BL, ln_g, ln_b, LNB);
  // out = x + LN@Wo + bo   (fp32 out, fp32 resid)
  k_gemm<3,false><<<dim3(D_/BN, M_/BM),256,0,stream>>>(
      LNB, D_, WoT, D_, bo, zeros, nullptr, nullptr, nullptr, nullptr, nullptr, out, x, D_, D_);
}

// Round 4
// 705.230 us; speedup vs baseline: 1.2621x; 1.0910x over previous
//
#include <hip/hip_runtime.h>
#include <hip/hip_bf16.h>
#include <math.h>

using bf16 = __hip_bfloat16;
typedef __bf16 v8bf __attribute__((ext_vector_type(8)));
typedef float v4f __attribute__((ext_vector_type(4)));

#define B_ 4
#define L_ 4096
#define D_ 1024
#define M_ (B_*L_)
#define CCH 128
#define LCH (L_/CCH)
#define NF 3584   // fused N: Wpv(1024) | Wk(1024) | Wkv(1024) | Wb1(512)

__device__ __forceinline__ float bf2f(bf16 v){ return __bfloat162float(v); }
__device__ __forceinline__ bf16 f2bf(float v){ return __float2bfloat16(v); }
__device__ __forceinline__ float us2f(ushort u){ union{unsigned u32; float f;}c; c.u32=((unsigned)u)<<16; return c.f; }
__device__ __forceinline__ ushort f2us(float v){ bf16 h=__float2bfloat16(v); return *(ushort*)&h; }
__device__ __forceinline__ float h2f(ushort u){ union{ushort s; _Float16 h;}c; c.s=u; return (float)c.h; }
__device__ __forceinline__ ushort f2h(float v){ union{ushort s; _Float16 h;}c; c.h=(_Float16)v; return c.s; }

// async global->LDS, 16B per lane, dest = uniform base + lane*16  [m97 pattern]
__device__ __forceinline__ void g2l16(const void* g, void* l){
  __builtin_amdgcn_global_load_lds(
    (const __attribute__((address_space(1))) unsigned int*)g,
    (__attribute__((address_space(3))) unsigned int*)l, 16, 0, 0);
}

// ---------------- zero a float region (ws is poisoned 0xAA each launch) ----------------
__global__ void k_zeroN(float* __restrict__ p, int n){
  int i = blockIdx.x*256 + threadIdx.x;
  if (i < n) p[i] = 0.0f;
}

// ---------------- x fp32 -> bf16 ----------------
__global__ void k_cvt(const float* __restrict__ in, bf16* __restrict__ out){
  int i = (blockIdx.x*256 + threadIdx.x)*4;
  float4 v = *(const float4*)(in + i);
  out[i]   = f2bf(v.x);
  out[i+1] = f2bf(v.y);
  out[i+2] = f2bf(v.z);
  out[i+3] = f2bf(v.w);
}

// ---------------- pos_phases fp32 -> fp16 ----------------
__global__ void k_cvt_pp(const float* __restrict__ in, ushort* __restrict__ out){
  int i = (blockIdx.x*256 + threadIdx.x)*4;
  float4 v = *(const float4*)(in + i);
  out[i]   = f2h(v.x);
  out[i+1] = f2h(v.y);
  out[i+2] = f2h(v.z);
  out[i+3] = f2h(v.w);
}

// ---------------- weight convert+transpose fp32 (R x C) -> bf16 (C x R) ----------------
__global__ void k_ctr(const float* __restrict__ in, bf16* __restrict__ out, int R, int C){
  __shared__ float tile[32][33];
  int c0 = blockIdx.x*32, r0 = blockIdx.y*32;
  #pragma unroll
  for (int i=0;i<32;i+=8)
    tile[threadIdx.y+i][threadIdx.x] = in[(size_t)(r0+threadIdx.y+i)*C + c0+threadIdx.x];
  __syncthreads();
  #pragma unroll
  for (int i=0;i<32;i+=8)
    out[(size_t)(c0+threadIdx.y+i)*R + r0+threadIdx.x] = f2bf(tile[threadIdx.x][threadIdx.y+i]);
}

// ---------------- pack fused bias [bpv|bk|bkv|bb1] ----------------
__global__ void k_pack_bias(const float* __restrict__ bpv, const float* __restrict__ bk,
                            const float* __restrict__ bkv, const float* __restrict__ bb1,
                            float* __restrict__ bf){
  int i = blockIdx.x*256 + threadIdx.x;
  float v;
  if (i < 1024) v = bpv[i];
  else if (i < 2048) v = bk[i-1024];
  else if (i < 3072) v = bkv[i-2048];
  else v = bb1[i-3072];
  bf[i] = v;
}

__device__ __forceinline__ float geluf(float v){
  return 0.5f*v*(1.0f + erff(v*0.70710678118654752f));
}
__device__ __forceinline__ float fast_tanh(float v){
  float a = fabsf(v);
  float e = __expf(-2.0f*a);
  float t = (1.0f - e)/(1.0f + e);
  return copysignf(t, v);
}

// ---------------- MFMA GEMM, global_load_lds staging (m97 structure) ----------------
// EPI 2: gate-fold (concat GEMM): per output gelu(v)*Wv2[col], reduce over cols -> atomicAdd gacc[row]
// EPI 3: outf[row*N+col] = v + residf (fp32 final)
// EPI 4: fused: bn<1024 -> PV bf16; <2048 -> KP fp16 = tanh(v)*pi; <3072 -> KV bf16;
//        else gelu -> dot Wb2f cols -> atomicAdd bwacc[row*2+{0,1}]
#define BM 128
#define BN 128
#define BK 32

template<int EPI, bool CONCAT>
__global__ __launch_bounds__(256) void k_gemm(
    const bf16* __restrict__ A, int lda,
    const bf16* __restrict__ Bt, int ldb,
    const float* __restrict__ bias,
    const bf16* __restrict__ zeros,
    bf16* __restrict__ o_pv, ushort* __restrict__ o_kp, bf16* __restrict__ o_kv,
    const float* __restrict__ Wv2, const float* __restrict__ Wb2f,
    float* __restrict__ gaccp, float* __restrict__ bwaccp,
    float* __restrict__ outf, const float* __restrict__ residf,
    int N, int Ktot)
{
  __shared__ __align__(16) ushort As[BM*BK];   // 128 x 32, unpadded (64B/row)
  __shared__ __align__(16) ushort Bs[BN*BK];
  int tid = threadIdx.x;
  int lane = tid & 63, wave = tid >> 6;
  int wm = wave & 1, wn = wave >> 1;
  int bn = blockIdx.x * BN, bm = blockIdx.y * BM;

  v4f zero = {0.f,0.f,0.f,0.f};
  v4f acc[4][4];
  #pragma unroll
  for (int i=0;i<4;i++)
    #pragma unroll
    for (int j=0;j<4;j++) acc[i][j] = zero;

  int sub = lane >> 2;        // 0..15 row-within-chunk
  int seg = lane & 3;         // 16B segment
  int mr = lane & 15, g4 = lane >> 4;

  auto mfma_step = [&](){
    v8bf af[4], bfr[4];
    #pragma unroll
    for (int i=0;i<4;i++) af[i]  = *(const v8bf*)&As[(wm*64 + i*16 + mr)*BK + g4*8];
    #pragma unroll
    for (int j=0;j<4;j++) bfr[j] = *(const v8bf*)&Bs[(wn*64 + j*16 + mr)*BK + g4*8];
    #pragma unroll
    for (int i=0;i<4;i++)
      #pragma unroll
      for (int j=0;j<4;j++)
        acc[i][j] = __builtin_amdgcn_mfma_f32_16x16x32_bf16(af[i], bfr[j], acc[i][j], 0, 0, 0);
  };
  auto stage_b = [&](int kk){
    #pragma unroll
    for (int s=0;s<2;s++){
      int q = wave*2 + s;          // 0..7 B chunks handled by waves 0..3 (2 each)
      int row = q*16 + sub;
      g2l16(Bt + (size_t)(bn+row)*ldb + (size_t)kk + seg*8, Bs + q*512);
    }
  };

  // phase 1: normal A (and all of it when !CONCAT)
  int k1 = CONCAT ? D_ : Ktot;
  for (int kk = 0; kk < k1; kk += BK) {
    #pragma unroll
    for (int s=0;s<2;s++){
      int q = wave*2 + s;
      int row = q*16 + sub;
      g2l16(A + (size_t)(bm+row)*lda + (size_t)kk + seg*8, As + q*512);
    }
    stage_b(kk);
    __syncthreads();
    mfma_step();
    __syncthreads();
  }
  if (CONCAT){
    // phase 2: shifted A (row m-1, zero when m % L == 0)
    for (int kk = D_; kk < Ktot; kk += BK) {
      #pragma unroll
      for (int s=0;s<2;s++){
        int q = wave*2 + s;
        int row = q*16 + sub;
        int m = bm + row;
        int l = m & (L_-1);
        const bf16* src = (l==0) ? (zeros + seg*8)
                                 : (A + (size_t)(m-1)*lda + (size_t)(kk - D_) + seg*8);
        g2l16(src, As + q*512);
      }
      stage_b(kk);
      __syncthreads();
      mfma_step();
      __syncthreads();
    }
  }

  // epilogue: C/D layout col=lane&15, row=(lane>>4)*4+reg  [verified m89/m91]
  int lr = lane >> 4, lc = lane & 15;
  if (EPI == 3){
    #pragma unroll
    for (int i=0;i<4;i++){
      #pragma unroll
      for (int j=0;j<4;j++){
        int col  = bn + wn*64 + j*16 + lc;
        int row0 = bm + wm*64 + i*16 + lr*4;
        float bias_v = bias[col];
        #pragma unroll
        for (int rr=0; rr<4; rr++){
          size_t idx = (size_t)(row0+rr)*N + col;
          outf[idx] = acc[i][j][rr] + bias_v + residf[idx];
        }
      }
    }
  } else if (EPI == 2){
    // gate fold: sum_col gelu(v)*Wg2[col] -> gacc[row]
    #pragma unroll
    for (int i=0;i<4;i++){
      float red[4] = {0.f,0.f,0.f,0.f};
      #pragma unroll
      for (int j=0;j<4;j++){
        int col = bn + wn*64 + j*16 + lc;
        float bias_v = bias[col];
        float wv = Wv2[col];
        #pragma unroll
        for (int rr=0; rr<4; rr++){
          float v = acc[i][j][rr] + bias_v;
          red[rr] += geluf(v) * wv;
        }
      }
      int row0 = bm + wm*64 + i*16 + lr*4;
      #pragma unroll
      for (int rr=0; rr<4; rr++){
        float r = red[rr];
        r += __shfl_xor(r,1); r += __shfl_xor(r,2);
        r += __shfl_xor(r,4); r += __shfl_xor(r,8);
        if (lc == 0) atomicAdd(&gaccp[row0+rr], r);
      }
    }
  } else { // EPI == 4
    if (bn < 3072){
      #pragma unroll
      for (int i=0;i<4;i++){
        #pragma unroll
        for (int j=0;j<4;j++){
          int col  = bn + wn*64 + j*16 + lc;
          int row0 = bm + wm*64 + i*16 + lr*4;
          float bias_v = bias[col];
          #pragma unroll
          for (int rr=0; rr<4; rr++){
            int row = row0 + rr;
            float v = acc[i][j][rr] + bias_v;
            if (bn < 1024) {
              o_pv[(size_t)row*1024 + col] = f2bf(v);
            } else if (bn < 2048) {
              float kp = fast_tanh(v) * 3.14159265358979323846f;
              o_kp[(size_t)row*1024 + (col-1024)] = f2h(kp);
            } else {
              o_kv[(size_t)row*1024 + (col-2048)] = f2bf(v);
            }
          }
        }
      }
    } else {
      // bw fold: two dots with Wb2 columns -> bwacc[row*2+c]
      #pragma unroll
      for (int i=0;i<4;i++){
        float r0[4] = {0.f,0.f,0.f,0.f};
        float r1[4] = {0.f,0.f,0.f,0.f};
        #pragma unroll
        for (int j=0;j<4;j++){
          int col = bn + wn*64 + j*16 + lc;
          float bias_v = bias[col];
          int kb = col - 3072;
          float w0 = Wb2f[kb*2], w1 = Wb2f[kb*2+1];
          #pragma unroll
          for (int rr=0; rr<4; rr++){
            float v = acc[i][j][rr] + bias_v;
            float gl = geluf(v);
            r0[rr] += gl*w0;
            r1[rr] += gl*w1;
          }
        }
        int row0 = bm + wm*64 + i*16 + lr*4;
        #pragma unroll
        for (int rr=0; rr<4; rr++){
          float a = r0[rr], b = r1[rr];
          a += __shfl_xor(a,1); a += __shfl_xor(a,2); a += __shfl_xor(a,4); a += __shfl_xor(a,8);
          b += __shfl_xor(b,1); b += __shfl_xor(b,2); b += __shfl_xor(b,4); b += __shfl_xor(b,8);
          if (lc == 0){
            atomicAdd(&bwaccp[(size_t)(row0+rr)*2],   a);
            atomicAdd(&bwaccp[(size_t)(row0+rr)*2+1], b);
          }
        }
      }
    }
  }
}

// ---------------- gate sigmoid + cumsum over L: one 1024-thread block per batch ----------------
__global__ __launch_bounds__(1024) void k_gscan(const float* __restrict__ gacc,
                                                const float* __restrict__ bg2,
                                                float* __restrict__ g, float* __restrict__ gc){
  __shared__ float sa[1024];
  int b = blockIdx.x, tid = threadIdx.x;
  int base = b*L_ + tid*4;
  float bb = bg2[0];
  float v0 = 1.f/(1.f+__expf(-(gacc[base]   + bb)));
  float v1 = 1.f/(1.f+__expf(-(gacc[base+1] + bb)));
  float v2 = 1.f/(1.f+__expf(-(gacc[base+2] + bb)));
  float v3 = 1.f/(1.f+__expf(-(gacc[base+3] + bb)));
  float s0 = v0, s1 = s0+v1, s2 = s1+v2, s3 = s2+v3;
  sa[tid] = s3; __syncthreads();
  for (int o=1;o<1024;o<<=1){
    float t = sa[tid] + ((tid>=o) ? sa[tid-o] : 0.f);
    __syncthreads();
    sa[tid] = t;
    __syncthreads();
  }
  float ex = sa[tid] - s3;
  g[base]=v0; g[base+1]=v1; g[base+2]=v2; g[base+3]=v3;
  gc[base]=ex+s0; gc[base+1]=ex+s1; gc[base+2]=ex+s2; gc[base+3]=ex+s3;
}

// ---------------- finish blend weights: softmax2 over bwacc ----------------
__global__ void k_finishbw(const float* __restrict__ bwacc, const float* __restrict__ bb2,
                           float2* __restrict__ bw){
  int t = blockIdx.x*256 + threadIdx.x;
  float a = bwacc[(size_t)t*2]   + bb2[0];
  float b = bwacc[(size_t)t*2+1] + bb2[1];
  float m = fmaxf(a,b);
  float e0 = __expf(a-m), e1 = __expf(b-m);
  float inv = 1.0f/(e0+e1);
  bw[t] = make_float2(e0*inv, e1*inv);
}

// ---------------- scan pass 1: per-chunk partial sums (4 channels/thread) ----------------
__global__ void k_scan_partial(const bf16* __restrict__ PV, const bf16* __restrict__ KV,
                               const ushort* __restrict__ KP, const float* __restrict__ g,
                               const ushort* __restrict__ ppH, float* __restrict__ PS){
  int tid = threadIdx.x;
  int d0 = tid*4;
  int j = blockIdx.x, b = blockIdx.y;
  int l0 = j*LCH;
  float pkc[4]={0,0,0,0}, pks[4]={0,0,0,0};
  if (l0 > 0){
    size_t pidx = ((size_t)b*L_ + l0-1)*D_ + d0;
    ushort4 up = *(const ushort4*)(KP+pidx);
    float ph0=h2f(up.x), ph1=h2f(up.y), ph2=h2f(up.z), ph3=h2f(up.w);
    __sincosf(ph0,&pks[0],&pkc[0]); __sincosf(ph1,&pks[1],&pkc[1]);
    __sincosf(ph2,&pks[2],&pkc[2]); __sincosf(ph3,&pks[3],&pkc[3]);
  }
  float p0[4]={0,0,0,0}, p1[4]={0,0,0,0}, p2[4]={0,0,0,0}, p3[4]={0,0,0,0};
  for (int l=l0; l<l0+LCH; l++){
    size_t idx = ((size_t)b*L_ + l)*D_ + d0;
    ushort4 upv = *(const ushort4*)(PV+idx);
    ushort4 ukv = *(const ushort4*)(KV+idx);
    ushort4 ukp = *(const ushort4*)(KP+idx);
    ushort4 upp = *(const ushort4*)(ppH + (size_t)l*D_ + d0);
    float gl = g[b*L_ + l];
    float pvv[4]={us2f(upv.x),us2f(upv.y),us2f(upv.z),us2f(upv.w)};
    float kvv[4]={us2f(ukv.x),us2f(ukv.y),us2f(ukv.z),us2f(ukv.w)};
    float kpv[4]={h2f(ukp.x),h2f(ukp.y),h2f(ukp.z),h2f(ukp.w)};
    float phv[4]={h2f(upp.x),h2f(upp.y),h2f(upp.z),h2f(upp.w)};
    #pragma unroll
    for (int c=0;c<4;c++){
      float sn, cs; __sincosf(phv[c], &sn, &cs);
      float kc, ks; __sincosf(kpv[c], &ks, &kc);
      float kvg = kvv[c]*gl;
      p0[c] += cs*pvv[c]; p1[c] += sn*pvv[c];
      p2[c] += pkc[c]*kvg; p3[c] += pks[c]*kvg;
      pkc[c]=kc; pks[c]=ks;
    }
  }
  size_t base = ((size_t)b*CCH + j)*D_ + d0;
  size_t plane = (size_t)B_*CCH*D_;
  #pragma unroll
  for (int c=0;c<4;c++){
    PS[0*plane + base + c] = p0[c];
    PS[1*plane + base + c] = p1[c];
    PS[2*plane + base + c] = p2[c];
    PS[3*plane + base + c] = p3[c];
  }
}

// ---------------- exclusive prefix over chunks (in place), one thread per (q,b,d) ----------------
__global__ void k_prefix(float* __restrict__ PS){
  int idx = blockIdx.x*256 + threadIdx.x;   // over 4*B_*D_
  int q = idx >> 12;
  int rem = idx & 4095;
  int b = rem >> 10, d = rem & 1023;
  size_t plane = (size_t)B_*CCH*D_;
  float* base = PS + (size_t)q*plane + (size_t)b*CCH*D_ + d;
  float s = 0.0f;
  for (int j=0;j<CCH;j+=4){
    float v0 = base[(size_t)(j  )*D_];
    float v1 = base[(size_t)(j+1)*D_];
    float v2 = base[(size_t)(j+2)*D_];
    float v3 = base[(size_t)(j+3)*D_];
    base[(size_t)(j  )*D_] = s; s += v0;
    base[(size_t)(j+1)*D_] = s; s += v1;
    base[(size_t)(j+2)*D_] = s; s += v2;
    base[(size_t)(j+3)*D_] = s; s += v3;
  }
}

// ---------------- scan pass 2: apply with carry + fused LayerNorm, emit LNB ----------------
__global__ void k_scan_apply(const bf16* __restrict__ PV, const bf16* __restrict__ KV,
                             const ushort* __restrict__ KP, const float* __restrict__ g,
                             const ushort* __restrict__ ppH, const float* __restrict__ PS,
                             const float* __restrict__ gc, const float2* __restrict__ bw,
                             const float* __restrict__ ln_g, const float* __restrict__ ln_b,
                             bf16* __restrict__ LNB){
  __shared__ float sA[4], sB[4];
  int tid = threadIdx.x;
  int d0 = tid*4;
  int j = blockIdx.x, b = blockIdx.y;
  int l0 = j*LCH;
  size_t base = ((size_t)b*CCH + j)*D_ + d0;
  size_t plane = (size_t)B_*CCH*D_;
  float mc[4], ms[4], kcm[4], ksm[4];
  #pragma unroll
  for (int c=0;c<4;c++){
    mc[c]  = PS[0*plane+base+c]; ms[c]  = PS[1*plane+base+c];
    kcm[c] = PS[2*plane+base+c]; ksm[c] = PS[3*plane+base+c];
  }
  float pkc[4]={0,0,0,0}, pks[4]={0,0,0,0};
  if (l0 > 0){
    size_t pidx = ((size_t)b*L_ + l0-1)*D_ + d0;
    ushort4 up = *(const ushort4*)(KP+pidx);
    float ph0=h2f(up.x), ph1=h2f(up.y), ph2=h2f(up.z), ph3=h2f(up.w);
    __sincosf(ph0,&pks[0],&pkc[0]); __sincosf(ph1,&pks[1],&pkc[1]);
    __sincosf(ph2,&pks[2],&pkc[2]); __sincosf(ph3,&pks[3],&pkc[3]);
  }
  float4 gv = *(const float4*)&ln_g[d0];
  float4 bv = *(const float4*)&ln_b[d0];
  int wv = tid >> 6, ln = tid & 63;
  for (int l=l0; l<l0+LCH; l++){
    size_t idx = ((size_t)b*L_ + l)*D_ + d0;
    ushort4 upv = *(const ushort4*)(PV+idx);
    ushort4 ukv = *(const ushort4*)(KV+idx);
    ushort4 ukp = *(const ushort4*)(KP+idx);
    ushort4 upp = *(const ushort4*)(ppH + (size_t)l*D_ + d0);
    float gl = g[b*L_ + l];
    float gcv = fmaxf(gc[b*L_+l], 1.0f);
    float rs = 0.03125f * rsqrtf(gcv);
    float2 w = bw[b*L_+l];
    float pvv[4]={us2f(upv.x),us2f(upv.y),us2f(upv.z),us2f(upv.w)};
    float kvv[4]={us2f(ukv.x),us2f(ukv.y),us2f(ukv.z),us2f(ukv.w)};
    float kpv[4]={h2f(ukp.x),h2f(ukp.y),h2f(ukp.z),h2f(ukp.w)};
    float phv[4]={h2f(upp.x),h2f(upp.y),h2f(upp.z),h2f(upp.w)};
    float bl[4];
    #pragma unroll
    for (int c=0;c<4;c++){
      float sn, cs; __sincosf(phv[c], &sn, &cs);
      float kc, ks; __sincosf(kpv[c], &ks, &kc);
      mc[c] += cs*pvv[c]; ms[c] += sn*pvv[c];
      float pos_ret = (cs*mc[c] + sn*ms[c]) * 0.03125f;
      float kvg = kvv[c]*gl;
      kcm[c] += pkc[c]*kvg; ksm[c] += pks[c]*kvg;
      float kv_ret = (kc*kcm[c] + ks*ksm[c]) * rs;
      bl[c] = w.x*pos_ret + w.y*kv_ret;
      pkc[c]=kc; pks[c]=ks;
    }
    // fused LayerNorm over D (block covers full row)
    float s  = bl[0]+bl[1]+bl[2]+bl[3];
    float s2 = bl[0]*bl[0]+bl[1]*bl[1]+bl[2]*bl[2]+bl[3]*bl[3];
    #pragma unroll
    for (int o=1;o<64;o<<=1){ s += __shfl_xor(s,o); s2 += __shfl_xor(s2,o); }
    if (ln == 0){ sA[wv] = s; sB[wv] = s2; }
    __syncthreads();
    float ts  = sA[0]+sA[1]+sA[2]+sA[3];
    float ts2 = sB[0]+sB[1]+sB[2]+sB[3];
    __syncthreads();
    float mu   = ts * (1.0f/D_);
    float var  = ts2 * (1.0f/D_) - mu*mu;
    float rstd = rsqrtf(var + 1e-5f);
    ushort4 ou;
    ou.x = f2us((bl[0]-mu)*rstd*gv.x + bv.x);
    ou.y = f2us((bl[1]-mu)*rstd*gv.y + bv.y);
    ou.z = f2us((bl[2]-mu)*rstd*gv.z + bv.z);
    ou.w = f2us((bl[3]-mu)*rstd*gv.w + bv.w);
    *(ushort4*)((ushort*)LNB + idx) = ou;
  }
}

extern "C" void kernel_launch(void* const* d_in, const int* in_sizes, int n_in,
                              void* d_out, int out_size, void* d_ws, size_t ws_size,
                              hipStream_t stream) {
  const float* x     = (const float*)d_in[0];
  const float* phases= (const float*)d_in[1];
  const float* Wpv   = (const float*)d_in[2];
  const float* bpv   = (const float*)d_in[3];
  const float* Wk    = (const float*)d_in[4];
  const float* bk    = (const float*)d_in[5];
  const float* Wkv   = (const float*)d_in[6];
  const float* bkv   = (const float*)d_in[7];
  const float* Wg1   = (const float*)d_in[8];
  const float* bg1   = (const float*)d_in[9];
  const float* Wg2   = (const float*)d_in[10];
  const float* bg2   = (const float*)d_in[11];
  const float* Wb1   = (const float*)d_in[12];
  const float* bb1   = (const float*)d_in[13];
  const float* Wb2   = (const float*)d_in[14];
  const float* bb2   = (const float*)d_in[15];
  const float* ln_g  = (const float*)d_in[16];
  const float* ln_b  = (const float*)d_in[17];
  const float* Wo    = (const float*)d_in[18];
  const float* bo    = (const float*)d_in[19];
  float* out = (float*)d_out;

  char* ws = (char*)d_ws;
  size_t off = 0;
  auto alloc = [&](size_t bytes)->char*{
    char* p = ws + off; off += (bytes + 255) & ~(size_t)255; return p;
  };
  bf16*  xb   = (bf16*)alloc((size_t)M_*D_*2);
  bf16*  WfT  = (bf16*)alloc((size_t)NF*D_*2);     // [WpvT|WkT|WkvT|Wb1T], ld=1024
  bf16*  Wg1T = (bf16*)alloc((size_t)D_*2*D_*2);   // 1024 x 2048
  bf16*  WoT  = (bf16*)alloc((size_t)D_*D_*2);
  bf16*  PV   = (bf16*)alloc((size_t)M_*D_*2);
  bf16*  KV   = (bf16*)alloc((size_t)M_*D_*2);
  ushort* KP  = (ushort*)alloc((size_t)M_*D_*2);   // fp16 key phase
  ushort* ppH = (ushort*)alloc((size_t)L_*D_*2);   // fp16 pos phases
  bf16*  LNB  = (bf16*)alloc((size_t)M_*D_*2);
  float* gbuf  = (float*)alloc((size_t)M_*4);
  float* gcbuf = (float*)alloc((size_t)M_*4);
  float2* bwbuf= (float2*)alloc((size_t)M_*8);
  float* PS    = (float*)alloc((size_t)4*B_*CCH*D_*4);
  float* biasF = (float*)alloc((size_t)NF*4);
  // contiguous zero region: gacc | bwacc | zeros
  float* gacc  = (float*)alloc((size_t)M_*4);          // 65536 B
  float* bwacc = (float*)alloc((size_t)M_*2*4);        // 131072 B
  bf16*  zeros = (bf16*)alloc(256);
  int nzero = (M_ + 2*M_ + 64);

  k_zeroN<<<(nzero+255)/256,256,0,stream>>>(gacc, nzero);
  k_cvt<<<(M_*D_)/1024, 256, 0, stream>>>(x, xb);
  k_cvt_pp<<<(L_*D_)/1024, 256, 0, stream>>>(phases, ppH);

  dim3 tb(32,8);
  k_ctr<<<dim3(D_/32, D_/32), tb, 0, stream>>>(Wpv, WfT,                       D_, D_);
  k_ctr<<<dim3(D_/32, D_/32), tb, 0, stream>>>(Wk,  WfT + (size_t)1024*D_,     D_, D_);
  k_ctr<<<dim3(D_/32, D_/32), tb, 0, stream>>>(Wkv, WfT + (size_t)2048*D_,     D_, D_);
  k_ctr<<<dim3((D_/2)/32, D_/32), tb, 0, stream>>>(Wb1, WfT + (size_t)3072*D_, D_, D_/2);
  k_ctr<<<dim3(D_/32, 2*D_/32), tb, 0, stream>>>(Wg1, Wg1T, 2*D_, D_);
  k_ctr<<<dim3(D_/32, D_/32), tb, 0, stream>>>(Wo,  WoT,  D_, D_);
  k_pack_bias<<<NF/256,256,0,stream>>>(bpv, bk, bkv, bb1, biasF);

  // fused PV/KP/KV + bw-fold : x @ [Wpv|Wk|Wkv|Wb1]  (M x 3584 x 1024)
  k_gemm<4,false><<<dim3(NF/BN, M_/BM),256,0,stream>>>(
      xb, D_, WfT, D_, biasF, zeros, PV, KP, KV, nullptr, Wb2, nullptr, bwacc,
      nullptr, nullptr, NF, D_);
  // concat GEMM with gate-fold: gacc[row] += sum gelu(...)*Wg2  (M x 1024 x 2048)
  k_gemm<2,true><<<dim3(D_/BN, M_/BM),256,0,stream>>>(
      xb, D_, Wg1T, 2*D_, bg1, zeros, nullptr, nullptr, nullptr, Wg2, nullptr, gacc, nullptr,
      nullptr, nullptr, D_, 2*D_);
  // gate sigmoid + cumsum
  k_gscan<<<B_,1024,0,stream>>>(gacc, bg2, gbuf, gcbuf);
  // blend weights softmax
  k_finishbw<<<M_/256,256,0,stream>>>(bwacc, bb2, bwbuf);
  // chunked scans -> LN'd blended
  dim3 sg(CCH, B_);
  k_scan_partial<<<sg,256,0,stream>>>(PV, KV, KP, gbuf, ppH, PS);
  k_prefix<<<(4*B_*D_)/256,256,0,stream>>>(PS);
  k_scan_apply<<<sg,256,0,stream>>>(PV, KV, KP, gbuf, ppH, PS, gcbuf, bwbuf, ln_g, ln_b, LNB);
  // out = x + LN@Wo + bo   (fp32 out, fp32 resid)
  k_gemm<3,false><<<dim3(D_/BN, M_/BM),256,0,stream>>>(
      LNB, D_, WoT, D_, bo, zeros, nullptr, nullptr, nullptr, nullptr, nullptr, nullptr, nullptr,
      out, x, D_, D_);
}